// Round 5
// baseline (295.949 us; speedup 1.0000x reference)
//
#include <hip/hip_runtime.h>
#include <cstdint>

// Problem constants
constexpr int B  = 256;
constexpr int W  = 256;
constexpr int F  = 256;
constexpr int H  = 4;
constexpr int D  = 8;
constexpr int HD = H * D;   // 32
#define NEG_SLOPE 0.2f

// ---------------------------------------------------------------------------
// Fully fused GAT kernel: one block per batch element b.
// block = 512 threads (8 waves): f = t & 255, half = t >> 8.
//
// Phase 1: feat[f, o] = sum_w x[b,w,f] * fc_w[o,w]   (w-split across halves,
//          LDS reduce), + el/er scores and their exp tables.
// Phase 2: edge softmax + aggregation (src-split across halves, LDS reduce,
//          normalize + bias -> gout in LDS).
// Phase 3: out[b,w,f] = sum_o gout[f,o] * proj_w[w,o] + proj_b[w]
//          (w-split across halves).
//
// LDS (96 KB, 1 block/CU):
//   attrow[h][s][12]: feat d0..7, el_raw, e^el, e^{.2 el}, pad  (broadcast reads)
//   red[o][f]:        phase-1 partials, then phase-2 partial/final gout (coalesced)
//   ertab[h][3][f]:   er raw / e^er / e^{.2 er}                  (coalesced)
//   psum[h][f]:       phase-2 partial softmax denominators       (coalesced)
// ---------------------------------------------------------------------------
__global__ __launch_bounds__(512) void k_fused(
    const float* __restrict__ x, const float* __restrict__ fc_w,
    const float* __restrict__ attn_l, const float* __restrict__ attn_r,
    const float* __restrict__ gat_bias,
    const float* __restrict__ proj_w, const float* __restrict__ proj_b,
    float* __restrict__ out)
{
    const int b    = blockIdx.x;
    const int t    = threadIdx.x;
    const int f    = t & 255;
    const int half = t >> 8;          // 0/1, wave-uniform

    __shared__ float attrow[H][F][12];   // 48 KB
    __shared__ float red[HD][F];         // 32 KB
    __shared__ float ertab[H][3][F];     // 12 KB
    __shared__ float psum[H][F];         //  4 KB

    float acc[HD];
#pragma unroll
    for (int o = 0; o < HD; ++o) acc[o] = 0.f;

    // ---------------- Phase 1: feat GEMM (w-split) ----------------
    {
        const float* xb = x + (size_t)b * W * F + f;
        const int wbeg = half * 128;
        constexpr int WS = 16;
        float cur[WS], nxt[WS];
#pragma unroll
        for (int j = 0; j < WS; ++j) cur[j] = xb[(size_t)(wbeg + j) * F];

        for (int w = wbeg; w < wbeg + 128; w += WS) {
            if (w + WS < wbeg + 128) {
#pragma unroll
                for (int j = 0; j < WS; ++j)
                    nxt[j] = xb[(size_t)(w + WS + j) * F];
            }
#pragma unroll
            for (int o = 0; o < HD; ++o) {
                float a = acc[o];
#pragma unroll
                for (int j = 0; j < WS; ++j)
                    a = fmaf(fc_w[o * W + w + j], cur[j], a);
                acc[o] = a;
            }
#pragma unroll
            for (int j = 0; j < WS; ++j) cur[j] = nxt[j];
        }
    }

    if (half == 1) {
#pragma unroll
        for (int o = 0; o < HD; ++o) red[o][f] = acc[o];
    }
    __syncthreads();

    if (half == 0) {
#pragma unroll
        for (int o = 0; o < HD; ++o) acc[o] += red[o][f];

        // publish feat rows (per head) for broadcast consumption
#pragma unroll
        for (int h = 0; h < H; ++h) {
            *(float4*)&attrow[h][f][0] =
                make_float4(acc[h * 8 + 0], acc[h * 8 + 1], acc[h * 8 + 2], acc[h * 8 + 3]);
            *(float4*)&attrow[h][f][4] =
                make_float4(acc[h * 8 + 4], acc[h * 8 + 5], acc[h * 8 + 6], acc[h * 8 + 7]);
        }

        // attention scores + exp tables
#pragma unroll
        for (int h = 0; h < H; ++h) {
            float sl = 0.f, sr = 0.f;
#pragma unroll
            for (int d = 0; d < D; ++d) {
                sl = fmaf(acc[h * 8 + d], attn_l[h * 8 + d], sl);
                sr = fmaf(acc[h * 8 + d], attn_r[h * 8 + d], sr);
            }
            attrow[h][f][8]  = sl;
            attrow[h][f][9]  = expf(sl);
            attrow[h][f][10] = expf(NEG_SLOPE * sl);
            attrow[h][f][11] = 0.f;
            ertab[h][0][f] = sr;
            ertab[h][1][f] = expf(sr);
            ertab[h][2][f] = expf(NEG_SLOPE * sr);
        }
    }
    __syncthreads();

    // ---------------- Phase 2: edge softmax + aggregate (src-split) --------
    // thread handles dst row i = f, src range [half*128, half*128+128)
    float err[H], erp[H], ern[H];
#pragma unroll
    for (int h = 0; h < H; ++h) {
        err[h] = ertab[h][0][f];
        erp[h] = ertab[h][1][f];
        ern[h] = ertab[h][2][f];
    }

    float sums[H];
#pragma unroll
    for (int o = 0; o < HD; ++o) acc[o] = 0.f;
#pragma unroll
    for (int h = 0; h < H; ++h) sums[h] = 0.f;

    const int sbeg = half * 128;
#pragma unroll
    for (int h = 0; h < H; ++h) {
        const float e_r = err[h], epv = erp[h], env = ern[h];
        float s0 = 0.f;
        float a0 = 0.f, a1 = 0.f, a2 = 0.f, a3 = 0.f,
              a4 = 0.f, a5 = 0.f, a6 = 0.f, a7 = 0.f;
        for (int s = sbeg; s < sbeg + 128; ++s) {
            const float4 f0 = *(const float4*)&attrow[h][s][0];
            const float4 f1 = *(const float4*)&attrow[h][s][4];
            const float4 e4 = *(const float4*)&attrow[h][s][8];
            const float v  = e4.x + e_r;
            const float p  = (v > 0.f) ? e4.y * epv : e4.z * env;
            s0 += p;
            a0 = fmaf(p, f0.x, a0);
            a1 = fmaf(p, f0.y, a1);
            a2 = fmaf(p, f0.z, a2);
            a3 = fmaf(p, f0.w, a3);
            a4 = fmaf(p, f1.x, a4);
            a5 = fmaf(p, f1.y, a5);
            a6 = fmaf(p, f1.z, a6);
            a7 = fmaf(p, f1.w, a7);
        }
        acc[h * 8 + 0] = a0; acc[h * 8 + 1] = a1;
        acc[h * 8 + 2] = a2; acc[h * 8 + 3] = a3;
        acc[h * 8 + 4] = a4; acc[h * 8 + 5] = a5;
        acc[h * 8 + 6] = a6; acc[h * 8 + 7] = a7;
        sums[h] = s0;
    }

    if (half == 1) {
#pragma unroll
        for (int o = 0; o < HD; ++o) red[o][f] = acc[o];
#pragma unroll
        for (int h = 0; h < H; ++h) psum[h][f] = sums[h];
    }
    __syncthreads();

    if (half == 0) {
#pragma unroll
        for (int o = 0; o < HD; ++o) acc[o] += red[o][f];
#pragma unroll
        for (int h = 0; h < H; ++h) sums[h] += psum[h][f];
#pragma unroll
        for (int h = 0; h < H; ++h) {
            const float inv = 1.f / sums[h];
#pragma unroll
            for (int d = 0; d < D; ++d)
                red[h * 8 + d][f] = fmaf(acc[h * 8 + d], inv, gat_bias[h * 8 + d]);
        }
    }
    __syncthreads();

    // ---------------- Phase 3: output projection (w-split) ----------------
    float g[HD];
#pragma unroll
    for (int o = 0; o < HD; ++o) g[o] = red[o][f];

    const int wbeg = half * 128;
    float* ob = out + (size_t)b * W * F + f;
    for (int w = wbeg; w < wbeg + 128; w += 2) {
        float a0 = proj_b[w];
        float a1 = proj_b[w + 1];
#pragma unroll
        for (int o = 0; o < HD; ++o) {
            a0 = fmaf(g[o], proj_w[w * HD + o], a0);
            a1 = fmaf(g[o], proj_w[(w + 1) * HD + o], a1);
        }
        ob[(size_t)w * F]       = a0;
        ob[(size_t)(w + 1) * F] = a1;
    }
}

// ---------------------------------------------------------------------------
extern "C" void kernel_launch(void* const* d_in, const int* in_sizes, int n_in,
                              void* d_out, int out_size, void* d_ws, size_t ws_size,
                              hipStream_t stream)
{
    const float* x      = (const float*)d_in[0];
    const float* fc_w   = (const float*)d_in[1];
    const float* attn_l = (const float*)d_in[2];
    const float* attn_r = (const float*)d_in[3];
    const float* gbias  = (const float*)d_in[4];
    const float* proj_w = (const float*)d_in[5];
    const float* proj_b = (const float*)d_in[6];
    float* out = (float*)d_out;

    k_fused<<<B, 512, 0, stream>>>(x, fc_w, attn_l, attn_r, gbias,
                                   proj_w, proj_b, out);
}

// Round 9
// 254.097 us; speedup vs baseline: 1.1647x; 1.1647x over previous
//
#include <hip/hip_runtime.h>
#include <cstdint>

// Problem constants
constexpr int B  = 256;
constexpr int W  = 256;
constexpr int F  = 256;
constexpr int H  = 4;
constexpr int D  = 8;
constexpr int HD = H * D;   // 32
#define NEG_SLOPE 0.2f

// ---------------------------------------------------------------------------
// LDS layout (float offsets). Total 20376 floats = 81504 B.
//   featg [256][33] : feat rows (pad 33: avoids 32-way conflicts on row reads);
//                     overwritten head-pair-wise by gout in phase 2.
//   el/er [4][256]  : attention scores.
//   sel   [2][260]  : descending-sorted (el - Mel) per head-slot; [256] is a
//                     -inf sentinel (9-step binary search may probe it).
//   scan  [2*18][260]: per head-slot 18 channels.
//       c=0..7 : A*feat_d  at rank r        (A  = e^{el-Mel} <= 1)
//       c=8    : A         at rank r
//       c=9..16: Bn*feat_d at rank 255-r    (Bn = e^{0.2(el-Mel)} <= 1)
//       c=17   : Bn        at rank 255-r
//   After forward exclusive scan: prefix at [k]; REVERSED channels give the
//   suffix sum directly at [256-k] (no subtraction -> no cancellation).
//   Scan region overlays the phase-1 reduce buffer.
// ---------------------------------------------------------------------------
constexpr int ROWP  = 33;
constexpr int FEATG = 0;                    // 256*33 = 8448
constexpr int ELOFF = 8448;                 // 4*256  = 1024
constexpr int EROFF = ELOFF + 1024;         // 4*256  = 1024
constexpr int SELO  = EROFF + 1024;         // 2*260  = 520
constexpr int SCANO = SELO + 520;           // 36*260 = 9360 (>= 8192 red overlay)
constexpr int CHLEN = 260;
constexpr int LDSF  = SCANO + 36 * CHLEN;   // 20376 floats = 81504 B

__global__ __launch_bounds__(512) void k_fused(
    const float* __restrict__ x, const float* __restrict__ fc_w,
    const float* __restrict__ attn_l, const float* __restrict__ attn_r,
    const float* __restrict__ gat_bias,
    const float* __restrict__ proj_w, const float* __restrict__ proj_b,
    float* __restrict__ out)
{
    __shared__ float lds[LDSF];

    const int b    = blockIdx.x;
    const int t    = threadIdx.x;
    const int f    = t & 255;
    const int half = t >> 8;          // 0/1, wave-uniform
    const int lane = t & 63;
    const int wave = t >> 6;          // 0..7

    // ================= Phase 1: feat GEMM (w-split halves) =================
    float acc[HD];
#pragma unroll
    for (int o = 0; o < HD; ++o) acc[o] = 0.f;

    {
        const float* xb = x + (size_t)b * W * F + f;
        const int wbeg = half * 128;
        constexpr int WS = 16;
        float cur[WS], nxt[WS];
#pragma unroll
        for (int j = 0; j < WS; ++j) cur[j] = *(xb + (size_t)(wbeg + j) * F);

        for (int w = wbeg; w < wbeg + 128; w += WS) {
            if (w + WS < wbeg + 128) {
#pragma unroll
                for (int j = 0; j < WS; ++j)
                    nxt[j] = *(xb + (size_t)(w + WS + j) * F);
            }
#pragma unroll
            for (int o = 0; o < HD; ++o) {
                float a = acc[o];
#pragma unroll
                for (int j = 0; j < WS; ++j)
                    a = fmaf(fc_w[o * W + w + j], cur[j], a);
                acc[o] = a;
            }
#pragma unroll
            for (int j = 0; j < WS; ++j) cur[j] = nxt[j];
        }
    }

    if (half == 1) {
#pragma unroll
        for (int o = 0; o < HD; ++o) lds[SCANO + o * 256 + f] = acc[o];
    }
    __syncthreads();

    if (half == 0) {
#pragma unroll
        for (int o = 0; o < HD; ++o) acc[o] += lds[SCANO + o * 256 + f];
#pragma unroll
        for (int o = 0; o < HD; ++o) lds[FEATG + f * ROWP + o] = acc[o];
#pragma unroll
        for (int h = 0; h < H; ++h) {
            float sl = 0.f, sr = 0.f;
#pragma unroll
            for (int d = 0; d < D; ++d) {
                sl = fmaf(acc[h * 8 + d], attn_l[h * 8 + d], sl);
                sr = fmaf(acc[h * 8 + d], attn_r[h * 8 + d], sr);
            }
            lds[ELOFF + h * 256 + f] = sl;
            lds[EROFF + h * 256 + f] = sr;
        }
    }
    __syncthreads();

    // ============ Phase 2: sorted-prefix-sum edge softmax ============
    // pass p handles heads {2p, 2p+1}; head slot hh = t>>8, src/dst = t&255.
    for (int p = 0; p < 2; ++p) {
        const int hh = t >> 8;
        const int h  = p * 2 + hh;
        const int s  = t & 255;

        // ---- (a) rank (descending, index tie-break) + head max + scatter ----
        const float e = lds[ELOFF + h * 256 + s];
        int r = 0;
        float m = -1e30f;
        {
            const float* elh = &lds[ELOFF + h * 256];
            for (int it = 0; it < 64; ++it) {
                const float4 q = *(const float4*)&elh[it * 4];
                const int i0 = it * 4;
                r += (q.x > e) || (q.x == e && (i0 + 0) < s);
                r += (q.y > e) || (q.y == e && (i0 + 1) < s);
                r += (q.z > e) || (q.z == e && (i0 + 2) < s);
                r += (q.w > e) || (q.w == e && (i0 + 3) < s);
                m = fmaxf(m, fmaxf(fmaxf(q.x, q.y), fmaxf(q.z, q.w)));
            }
        }
        const float elc = e - m;                 // <= 0
        const float A   = expf(elc);             // <= 1
        const float Bn  = expf(NEG_SLOPE * elc); // <= 1
        lds[SELO + hh * CHLEN + r] = elc;
        if (s == 0) lds[SELO + hh * CHLEN + 256] = -3.4e38f;  // search sentinel
        {
            float* sc = &lds[SCANO + hh * 18 * CHLEN];
            const float* fr = &lds[FEATG + s * ROWP + h * 8];
            const int rr = 255 - r;              // reversed slot for suffix scan
#pragma unroll
            for (int d = 0; d < D; ++d) {
                const float fd = fr[d];
                sc[d * CHLEN + r]        = A * fd;
                sc[(9 + d) * CHLEN + rr] = Bn * fd;
            }
            sc[8 * CHLEN + r]   = A;
            sc[17 * CHLEN + rr] = Bn;
        }
        __syncthreads();

        // ---- (b) exclusive-prefix wave-scans over 36 channels ----
        for (int c36 = wave; c36 < 36; c36 += 8) {
            float* cb = &lds[SCANO + c36 * CHLEN];
            float4 v = *(float4*)&cb[lane * 4];
            const float t0 = v.x;
            const float t1 = t0 + v.y;
            const float t2 = t1 + v.z;
            const float t3 = t2 + v.w;
            float xs = t3;
#pragma unroll
            for (int off = 1; off < 64; off <<= 1) {
                const float n = __shfl_up(xs, (unsigned)off, 64);
                if (lane >= off) xs += n;
            }
            const float excl = xs - t3;
            *(float4*)&cb[lane * 4] =
                make_float4(excl, excl + t0, excl + t1, excl + t2);
            if (lane == 63) cb[256] = excl + t3;
        }
        __syncthreads();

        // ---- (c) per-dst binary search (9 steps: 257 candidates) + combine ----
        {
            const int i = s;
            const float erc  = lds[EROFF + h * 256 + i] + m;
            const float tthr = -erc;
            // common factor e^{erc} cancels in num/den; q = Dn/C = e^{-0.8 erc}
            const float q = expf(-0.8f * erc);

            const float* selh = &lds[SELO + hh * CHLEN];
            int lo = 0, hi = 256;
#pragma unroll
            for (int st = 0; st < 9; ++st) {
                const int mid = (lo + hi) >> 1;
                const bool g = selh[mid] > tthr;
                lo = g ? mid + 1 : lo;
                hi = g ? hi : mid;
            }
            const int k  = lo;        // positive-branch prefix length
            const int ks = 256 - k;   // suffix lookup index (reversed channels)

            const float* sc = &lds[SCANO + hh * 18 * CHLEN];
            const float den = sc[8 * CHLEN + k] + q * sc[17 * CHLEN + ks];
            const float invden = 1.f / den;

            float* go = &lds[FEATG + i * ROWP + h * 8];
#pragma unroll
            for (int d = 0; d < D; ++d) {
                const float num = sc[d * CHLEN + k] + q * sc[(9 + d) * CHLEN + ks];
                go[d] = fmaf(num, invden, gat_bias[h * 8 + d]);
            }
        }
        __syncthreads();
    }

    // ================= Phase 3: output projection (w-split) =================
    float g[HD];
#pragma unroll
    for (int o = 0; o < HD; ++o) g[o] = lds[FEATG + f * ROWP + o];

    const int wbeg = half * 128;
    float* ob = out + (size_t)b * W * F + f;
    for (int w = wbeg; w < wbeg + 128; w += 2) {
        float a0 = proj_b[w];
        float a1 = proj_b[w + 1];
#pragma unroll
        for (int o = 0; o < HD; ++o) {
            a0 = fmaf(g[o], proj_w[w * HD + o], a0);
            a1 = fmaf(g[o], proj_w[(w + 1) * HD + o], a1);
        }
        ob[(size_t)w * F]       = a0;
        ob[(size_t)(w + 1) * F] = a1;
    }
}

// ---------------------------------------------------------------------------
extern "C" void kernel_launch(void* const* d_in, const int* in_sizes, int n_in,
                              void* d_out, int out_size, void* d_ws, size_t ws_size,
                              hipStream_t stream)
{
    const float* x      = (const float*)d_in[0];
    const float* fc_w   = (const float*)d_in[1];
    const float* attn_l = (const float*)d_in[2];
    const float* attn_r = (const float*)d_in[3];
    const float* gbias  = (const float*)d_in[4];
    const float* proj_w = (const float*)d_in[5];
    const float* proj_b = (const float*)d_in[6];
    float* out = (float*)d_out;

    k_fused<<<B, 512, 0, stream>>>(x, fc_w, attn_l, attn_r, gbias,
                                   proj_w, proj_b, out);
}

// Round 10
// 195.652 us; speedup vs baseline: 1.5126x; 1.2987x over previous
//
#include <hip/hip_runtime.h>
#include <cstdint>

// Problem constants
constexpr int B  = 256;
constexpr int W  = 256;
constexpr int F  = 256;
constexpr int H  = 4;
constexpr int D  = 8;
constexpr int HD = H * D;   // 32
#define NEG_SLOPE 0.2f

// ---------------------------------------------------------------------------
// Workspace layout (floats):
//   feath [H][B][F][8] : per-head feat rows (contiguous 32B per (f))  8.4 MB
//   elw   [H][B][F]    : src scores                                   1.05 MB
//   erw   [H][B][F]    : dst scores                                   1.05 MB
//   gout  [B][F][32]   : aggregated head outputs (+bias)              8.4 MB
// ---------------------------------------------------------------------------

// ---------------------------------------------------------------------------
// k_feat: one block per (b, head). 256 threads, thread = f.
//   feat[f, o] = sum_w x[b,w,f] * fc_w[h*8+o, w],  o in [0,8)
//   el/er dot products for this head.
// grid = (B, H) = 1024 blocks -> 4 blocks/CU -> 16 waves/CU (4/SIMD).
// 32-deep load double-buffer: 32 dword loads in flight per wave; per-batch
// FMA issue = 8 o x 32 w x 2 cyc x 4 waves/SIMD = 2048 cyc >> ~900 cyc HBM.
// Same-b blocks (y=0..3) are 256 apart in linear id (=0 mod 8) -> same XCD,
// so the 4x x re-read is served by that XCD's L2/L3.
// ---------------------------------------------------------------------------
__global__ __launch_bounds__(256) void k_feat(
    const float* __restrict__ x, const float* __restrict__ fc_w,
    const float* __restrict__ attn_l, const float* __restrict__ attn_r,
    float* __restrict__ feath, float* __restrict__ elw, float* __restrict__ erw)
{
    const int b = blockIdx.x;
    const int h = blockIdx.y;
    const int f = threadIdx.x;

    const float* xb = x + (size_t)b * W * F + f;
    const float* fw = fc_w + (size_t)(h * D) * W;   // 8 rows of length W

    float acc[D];
#pragma unroll
    for (int o = 0; o < D; ++o) acc[o] = 0.f;

    constexpr int WS = 32;
    float cur[WS], nxt[WS];
#pragma unroll
    for (int j = 0; j < WS; ++j) cur[j] = xb[(size_t)j * F];

    for (int w = 0; w < W; w += WS) {
        if (w + WS < W) {
#pragma unroll
            for (int j = 0; j < WS; ++j)
                nxt[j] = xb[(size_t)(w + WS + j) * F];
        }
#pragma unroll
        for (int o = 0; o < D; ++o) {
            float a = acc[o];
#pragma unroll
            for (int j = 0; j < WS; ++j)
                a = fmaf(fw[o * W + w + j], cur[j], a);
            acc[o] = a;
        }
        if (w + WS < W) {
#pragma unroll
            for (int j = 0; j < WS; ++j) cur[j] = nxt[j];
        }
    }

    float el = 0.f, er = 0.f;
#pragma unroll
    for (int d = 0; d < D; ++d) {
        el = fmaf(acc[d], attn_l[h * D + d], el);
        er = fmaf(acc[d], attn_r[h * D + d], er);
    }

    float* fr = feath + ((size_t)(h * B + b) * F + f) * D;
    *(float4*)(fr + 0) = make_float4(acc[0], acc[1], acc[2], acc[3]);
    *(float4*)(fr + 4) = make_float4(acc[4], acc[5], acc[6], acc[7]);
    elw[(size_t)(h * B + b) * F + f] = el;
    erw[(size_t)(h * B + b) * F + f] = er;
}

// ---------------------------------------------------------------------------
// k_attn: sorted-prefix-scan edge softmax, one block per (h, b). 256 threads.
//   p[i,s] = exp(leaky_relu(el[s]+er[i])); gout[i] = sum_s p*feat[s] / sum_s p.
// Sort src by el (rank via counting); positive branch = prefix of sorted
// order. Exclusive scans of A*feat (A=e^{el-M}<=1) and reversed Bn*feat
// (Bn=e^{.2(el-M)}) give each dst's sums via one 9-step binary search.
// Thread s owns feat row s + er[i=s] in REGISTERS (no LDS for them).
// LDS = el[256] + sel[264] + scan[18][260] = 20.8 KB -> 4 blocks/CU.
// ---------------------------------------------------------------------------
constexpr int ELOFF = 0;
constexpr int SELO  = 256;
constexpr int SCANO = 520;
constexpr int CHLEN = 260;
constexpr int LDSF  = SCANO + 18 * CHLEN;   // 5200 floats = 20.8 KB

__global__ __launch_bounds__(256) void k_attn(
    const float* __restrict__ feath, const float* __restrict__ elw,
    const float* __restrict__ erw, const float* __restrict__ gat_bias,
    float* __restrict__ gout)
{
    __shared__ float lds[LDSF];

    const int h = blockIdx.x;
    const int b = blockIdx.y;
    const int s = threadIdx.x;
    const int lane = s & 63;
    const int wave = s >> 6;   // 0..3

    // stage: own feat row + scores (feat row stays in regs)
    const float* fr = feath + ((size_t)(h * B + b) * F + s) * D;
    const float4 f03 = *(const float4*)(fr + 0);
    const float4 f47 = *(const float4*)(fr + 4);
    const float e    = elw[(size_t)(h * B + b) * F + s];
    const float er_i = erw[(size_t)(h * B + b) * F + s];
    lds[ELOFF + s] = e;
    __syncthreads();

    // rank (descending, index tie-break) + head max
    int r = 0;
    float m = -1e30f;
    {
        const float* elh = &lds[ELOFF];
        for (int it = 0; it < 64; ++it) {
            const float4 q = *(const float4*)&elh[it * 4];
            const int i0 = it * 4;
            r += (q.x > e) || (q.x == e && (i0 + 0) < s);
            r += (q.y > e) || (q.y == e && (i0 + 1) < s);
            r += (q.z > e) || (q.z == e && (i0 + 2) < s);
            r += (q.w > e) || (q.w == e && (i0 + 3) < s);
            m = fmaxf(m, fmaxf(fmaxf(q.x, q.y), fmaxf(q.z, q.w)));
        }
    }
    const float elc = e - m;                 // <= 0
    const float A   = expf(elc);             // <= 1
    const float Bn  = expf(NEG_SLOPE * elc); // <= 1
    lds[SELO + r] = elc;
    if (s == 0) lds[SELO + 256] = -3.4e38f;  // 9-step search sentinel
    {
        float* sc = &lds[SCANO];
        const int rr = 255 - r;              // reversed slot -> suffix scan
        const float fv[D] = {f03.x, f03.y, f03.z, f03.w, f47.x, f47.y, f47.z, f47.w};
#pragma unroll
        for (int d = 0; d < D; ++d) {
            sc[d * CHLEN + r]        = A * fv[d];
            sc[(9 + d) * CHLEN + rr] = Bn * fv[d];
        }
        sc[8 * CHLEN + r]   = A;
        sc[17 * CHLEN + rr] = Bn;
    }
    __syncthreads();

    // exclusive-prefix wave-scans over 18 channels (4 waves)
    for (int c = wave; c < 18; c += 4) {
        float* cb = &lds[SCANO + c * CHLEN];
        float4 v = *(float4*)&cb[lane * 4];
        const float t0 = v.x;
        const float t1 = t0 + v.y;
        const float t2 = t1 + v.z;
        const float t3 = t2 + v.w;
        float xs = t3;
#pragma unroll
        for (int off = 1; off < 64; off <<= 1) {
            const float n = __shfl_up(xs, (unsigned)off, 64);
            if (lane >= off) xs += n;
        }
        const float excl = xs - t3;
        *(float4*)&cb[lane * 4] =
            make_float4(excl, excl + t0, excl + t1, excl + t2);
        if (lane == 63) cb[256] = excl + t3;
    }
    __syncthreads();

    // per-dst binary search (9 steps: 257 candidates) + combine
    {
        const int i = s;
        const float erc  = er_i + m;
        const float tthr = -erc;
        // common e^{erc} cancels in num/den; q = e^{-0.8 erc}
        const float q = expf(-0.8f * erc);

        const float* selh = &lds[SELO];
        int lo = 0, hi = 256;
#pragma unroll
        for (int st = 0; st < 9; ++st) {
            const int mid = (lo + hi) >> 1;
            const bool g = selh[mid] > tthr;
            lo = g ? mid + 1 : lo;
            hi = g ? hi : mid;
        }
        const int k  = lo;        // positive-branch prefix length
        const int ks = 256 - k;   // suffix index in reversed channels

        const float* sc = &lds[SCANO];
        const float den = sc[8 * CHLEN + k] + q * sc[17 * CHLEN + ks];
        const float invden = 1.f / den;

        float o8[D];
#pragma unroll
        for (int d = 0; d < D; ++d) {
            const float num = sc[d * CHLEN + k] + q * sc[(9 + d) * CHLEN + ks];
            o8[d] = fmaf(num, invden, gat_bias[h * D + d]);
        }
        float* go = gout + ((size_t)b * F + i) * HD + h * D;
        *(float4*)(go + 0) = make_float4(o8[0], o8[1], o8[2], o8[3]);
        *(float4*)(go + 4) = make_float4(o8[4], o8[5], o8[6], o8[7]);
    }
}

// ---------------------------------------------------------------------------
// k_proj: out[b,w,f] = sum_o gout[b,f,o]*proj_w[w,o] + proj_b[w]
// grid = (B, 16): 16 w's per block, 4096 blocks -> occupancy-rich.
// Same-b blocks same XCD -> gout row re-reads hit L2.
// ---------------------------------------------------------------------------
__global__ __launch_bounds__(256) void k_proj(
    const float* __restrict__ gout, const float* __restrict__ proj_w,
    const float* __restrict__ proj_b, float* __restrict__ out)
{
    const int b  = blockIdx.x;
    const int wq = blockIdx.y;   // 0..15
    const int f  = threadIdx.x;

    float g[HD];
    const float4* gp = (const float4*)(gout + ((size_t)b * F + f) * HD);
#pragma unroll
    for (int o = 0; o < HD; o += 4) {
        float4 v = gp[o / 4];
        g[o] = v.x; g[o + 1] = v.y; g[o + 2] = v.z; g[o + 3] = v.w;
    }

    const int wbeg = wq * 16;
    float* ob = out + (size_t)b * W * F + f;
#pragma unroll 2
    for (int w = wbeg; w < wbeg + 16; w += 2) {
        float a0 = proj_b[w];
        float a1 = proj_b[w + 1];
#pragma unroll
        for (int o = 0; o < HD; ++o) {
            a0 = fmaf(g[o], proj_w[w * HD + o], a0);
            a1 = fmaf(g[o], proj_w[(w + 1) * HD + o], a1);
        }
        ob[(size_t)w * F]       = a0;
        ob[(size_t)(w + 1) * F] = a1;
    }
}

// ---------------------------------------------------------------------------
extern "C" void kernel_launch(void* const* d_in, const int* in_sizes, int n_in,
                              void* d_out, int out_size, void* d_ws, size_t ws_size,
                              hipStream_t stream)
{
    const float* x      = (const float*)d_in[0];
    const float* fc_w   = (const float*)d_in[1];
    const float* attn_l = (const float*)d_in[2];
    const float* attn_r = (const float*)d_in[3];
    const float* gbias  = (const float*)d_in[4];
    const float* proj_w = (const float*)d_in[5];
    const float* proj_b = (const float*)d_in[6];
    float* out = (float*)d_out;

    // workspace: feath[H*B*F*8] | elw[H*B*F] | erw[H*B*F] | gout[B*F*32]
    float* feath = (float*)d_ws;
    float* elw   = feath + (size_t)H * B * F * D;
    float* erw   = elw   + (size_t)H * B * F;
    float* gout  = erw   + (size_t)H * B * F;

    k_feat<<<dim3(B, H), 256, 0, stream>>>(x, fc_w, attn_l, attn_r,
                                           feath, elw, erw);
    k_attn<<<dim3(H, B), 256, 0, stream>>>(feath, elw, erw, gbias, gout);
    k_proj<<<dim3(B, 16), 256, 0, stream>>>(gout, proj_w, proj_b, out);
}